// Round 9
// baseline (1003.005 us; speedup 1.0000x reference)
//
#include <hip/hip_runtime.h>

typedef _Float16 f16;
typedef f16 f16x8 __attribute__((ext_vector_type(8)));
typedef f16 f16x4 __attribute__((ext_vector_type(4)));
typedef float f32x4 __attribute__((ext_vector_type(4)));
typedef unsigned int u32x4 __attribute__((ext_vector_type(4)));

#define BDIM 16
#define MDIM 4
#define NDIM 4096
#define NB   64
#define NTILES (NDIM/NB)          // 64
#define NBMT  (BDIM*MDIM*NTILES)  // 4096

#define MFMA16(a,b,c) __builtin_amdgcn_mfma_f32_16x16x32_f16(a, b, c, 0, 0, 0)

// ---------------- prep: fp32 weights -> f16 fragment layout ----------------
// W1s: [e][kb(64)][o(128)][ki(8)]   W2s: [e][kb(16)][o(48)][ki(8)]
// W3s: [e][kb(8)][o(16)][ki(8)] (K padded 48->64 with zeros)
__global__ __launch_bounds__(256) void prep_kernel(
    const float* __restrict__ W1, const float* __restrict__ W2, const float* __restrict__ W3,
    f16* __restrict__ W1s, f16* __restrict__ W2s, f16* __restrict__ W3s)
{
  int i = blockIdx.x * 256 + threadIdx.x;
  if (i < 262144) {
    int ki = i & 7; int rest = i >> 3;
    int o = rest & 127; rest >>= 7;
    int kb = rest & 63; int e = rest >> 6;
    W1s[i] = (f16)W1[(e*128 + o)*512 + kb*8 + ki];
  } else if (i < 262144 + 24576) {
    int j = i - 262144;
    int ki = j & 7; int rest = j >> 3;
    int o = rest % 48; rest /= 48;
    int kb = rest & 15; int e = rest >> 4;
    W2s[j] = (f16)W2[(e*48 + o)*128 + kb*8 + ki];
  } else if (i < 262144 + 24576 + 4096) {
    int j = i - 262144 - 24576;
    int ki = j & 7; int rest = j >> 3;
    int o = rest & 15; rest >>= 4;
    int kb = rest & 7; int e = rest >> 3;
    int k = kb*8 + ki;
    W3s[j] = (k < 48) ? (f16)W3[(e*16 + o)*48 + k] : (f16)0.f;
  }
}

// ---------------- xprep: coalesced read + register transpose --------------
// block = (bm, cb): 8 channels x all 4096 n; 1024 threads, one n-quad each.
// Plain (cached) loads/stores — nt hurt here (R8). Emits pooled sums too.
__global__ __launch_bounds__(1024) void xprep_kernel(
    const float* __restrict__ x, f16* __restrict__ Xt, float* __restrict__ partial)
{
  const int bid = blockIdx.x;            // bm*64 + cb
  const int cb  = bid & 63;
  const int bm  = bid >> 6;              // b*4 + m
  const int b   = bm >> 2, m = bm & 3;
  const int t   = threadIdx.x;
  const int lane = t & 63, wid = t >> 6;

  __shared__ float red[16][8];

  const int n0 = t*4;
  f32x4 v[8];
  #pragma unroll
  for (int ci = 0; ci < 8; ++ci)
    v[ci] = *(const f32x4*)(x + (((size_t)(b*512 + cb*8 + ci))*4 + m)*4096 + n0);

  float s[8];
  #pragma unroll
  for (int ci = 0; ci < 8; ++ci) s[ci] = v[ci][0]+v[ci][1]+v[ci][2]+v[ci][3];

  const int tile = n0 >> 6, p = n0 & 63;
  const size_t obase = (((size_t)bm*64 + tile)*64 + cb)*64;
  #pragma unroll
  for (int i = 0; i < 4; ++i) {
    f16x8 o;
    #pragma unroll
    for (int ci = 0; ci < 8; ++ci) o[ci] = (f16)v[ci][i];
    *(f16x8*)(Xt + (obase + p + i)*8) = o;
  }

  #pragma unroll
  for (int off = 32; off; off >>= 1)
    #pragma unroll
    for (int ci = 0; ci < 8; ++ci) s[ci] += __shfl_down(s[ci], off);
  if (lane == 0)
    #pragma unroll
    for (int ci = 0; ci < 8; ++ci) red[wid][ci] = s[ci];
  __syncthreads();
  if (t < 8) {
    float a = 0.f;
    #pragma unroll
    for (int w = 0; w < 16; ++w) a += red[w][t];
    partial[(size_t)bm*512 + cb*8 + t] = a;
  }
}

// ---------------- gate: pooled -> MLP + softmax (torch reshape quirk) -----
__global__ __launch_bounds__(256) void gate_kernel(
    const float* __restrict__ partial, const float* __restrict__ Wg1,
    const float* __restrict__ bg1, const float* __restrict__ Wg2,
    const float* __restrict__ bg2, float* __restrict__ wgt)
{
  __shared__ float pl[512*4];   // [c][m]
  __shared__ float g1[128*4];   // [o][m]
  __shared__ float g2[16];      // [e][m]
  const int b = blockIdx.x, tid = threadIdx.x;
  for (int i = tid; i < 2048; i += 256) {
    int c = i >> 2, mm = i & 3;
    pl[c*4 + mm] = partial[(size_t)(b*4 + mm)*512 + c] * (1.0f/4096.0f);
  }
  __syncthreads();
  #pragma unroll
  for (int u = 0; u < 2; ++u) {
    int idx = u*256 + tid;
    int o = idx >> 2, mm = idx & 3;
    float acc = bg1[o];
    for (int c = 0; c < 512; ++c) acc += Wg1[o*512 + c] * pl[c*4 + mm];
    g1[o*4 + mm] = fmaxf(acc, 0.f);
  }
  __syncthreads();
  if (tid < 16) {
    int e = tid >> 2, mm = tid & 3;
    float acc = bg2[e];
    for (int o = 0; o < 128; ++o) acc += Wg2[e*128 + o] * g1[o*4 + mm];
    g2[e*4 + mm] = acc;
  }
  __syncthreads();
  if (tid < 4) {
    int mrow = tid;
    float v0 = g2[mrow*4+0], v1 = g2[mrow*4+1], v2 = g2[mrow*4+2], v3 = g2[mrow*4+3];
    float mx = fmaxf(fmaxf(v0,v1), fmaxf(v2,v3));
    float e0 = expf(v0-mx), e1 = expf(v1-mx), e2 = expf(v2-mx), e3 = expf(v3-mx);
    float inv = 1.0f / (e0+e1+e2+e3);
    wgt[b*16 + mrow*4 + 0] = e0*inv;
    wgt[b*16 + mrow*4 + 1] = e1*inv;
    wgt[b*16 + mrow*4 + 2] = e2*inv;
    wgt[b*16 + mrow*4 + 3] = e3*inv;
  }
}

// ---------------- moe: T=2 tiles/pass, W reg-prefetch, combine fused -------
// 256 blocks x 1024 thr (16 waves), 160 KiB LDS, 1 block/CU, 8 pair-iters.
// LDS: XA 64K | XB 64K | H2 32K. Phase A joint over both tiles: each W1
// A-fragment feeds 16 MFMAs (2 tiles x 2 experts x 4 pt) -> W logical
// traffic halved to 1 GiB; depth-1 register prefetch of next ks's A-frags
// hides L2/L3 latency. H1A/H1B overlay XA/XB in Phase B.
__global__ __launch_bounds__(1024, 4) void moe_kernel(
    const f16* __restrict__ Xt,
    const f16* __restrict__ W1s, const f16* __restrict__ W2s, const f16* __restrict__ W3s,
    const float* __restrict__ b1, const float* __restrict__ b2, const float* __restrict__ b3,
    const float* __restrict__ wgt, float* __restrict__ out)
{
  extern __shared__ __align__(16) char smem[];     // 163840 B
  char* XA = smem;
  char* XB = smem + 65536;
  char* H2 = smem + 131072;

  const int tid  = threadIdx.x;
  const int wave = tid >> 6, lane = tid & 63;
  const int g = lane >> 4, r = lane & 15;
  const int eh = wave >> 3;                        // experts 2eh, 2eh+1
  const int o0 = (wave & 7) * 16;
  const int e0 = eh*2, e1 = eh*2 + 1;

  // zero H2's K-pad (hb 6,7 per e) once; L2 never writes hb>5
  if (tid < 512) {
    int e = tid >> 7, off = tid & 127;
    *(u32x4*)(H2 + e*8192 + 6144 + off*16) = (u32x4){0u,0u,0u,0u};
  }

  const int bmt0 = blockIdx.x * 16;
  // prologue: stage pair 0
  {
    const u32x4* sA = (const u32x4*)(Xt + (size_t)bmt0 * 32768);
    const u32x4* sB = (const u32x4*)(Xt + (size_t)(bmt0+1) * 32768);
    #pragma unroll
    for (int j = 0; j < 4; ++j) {
      *(u32x4*)(XA + tid*16 + j*16384) = __builtin_nontemporal_load(sA + tid + j*1024);
      *(u32x4*)(XB + tid*16 + j*16384) = __builtin_nontemporal_load(sB + tid + j*1024);
    }
  }

  #pragma unroll 1
  for (int it = 0; it < 8; ++it) {
    const int bmtA = bmt0 + it*2, bmtB = bmtA + 1;
    const int tileA = bmtA & 63, mA = (bmtA >> 6) & 3, bA = bmtA >> 8;
    const int tileB = bmtB & 63, mB = (bmtB >> 6) & 3, bB = bmtB >> 8;

    __syncthreads();                   // staging visible (prologue or tail)

    // ---- Phase A: joint L1 over both tiles; barrier-free
    f32x4 acc[2][4], bcc[2][4];
    #pragma unroll
    for (int i = 0; i < 2; ++i)
      #pragma unroll
      for (int pt = 0; pt < 4; ++pt) {
        acc[i][pt] = (f32x4){0.f,0.f,0.f,0.f};
        bcc[i][pt] = (f32x4){0.f,0.f,0.f,0.f};
      }

    const f16* Wb = W1s + (size_t)(o0 + r)*8;
    f16x8 awc0 = *(const f16x8*)(Wb + (size_t)((e0*64 + g)*128)*8);
    f16x8 awc1 = *(const f16x8*)(Wb + (size_t)((e1*64 + g)*128)*8);

    #pragma unroll
    for (int ks = 0; ks < 16; ++ks) {
      f16x8 awn0, awn1;
      if (ks < 15) {                   // depth-1 prefetch of next A-frags
        const int kbn = (ks+1)*4 + g;
        awn0 = *(const f16x8*)(Wb + (size_t)((e0*64 + kbn)*128)*8);
        awn1 = *(const f16x8*)(Wb + (size_t)((e1*64 + kbn)*128)*8);
      }
      const int kb = ks*4 + g;
      #pragma unroll
      for (int pt = 0; pt < 4; ++pt) {
        f16x8 bfA = *(const f16x8*)(XA + (kb*64 + pt*16 + r)*16);
        acc[0][pt] = MFMA16(awc0, bfA, acc[0][pt]);
        acc[1][pt] = MFMA16(awc1, bfA, acc[1][pt]);
        f16x8 bfB = *(const f16x8*)(XB + (kb*64 + pt*16 + r)*16);
        bcc[0][pt] = MFMA16(awc0, bfB, bcc[0][pt]);
        bcc[1][pt] = MFMA16(awc1, bfB, bcc[1][pt]);
      }
      awc0 = awn0; awc1 = awn1;
    }
    __syncthreads();                   // all reads of XA/XB done

    // ---- H1A -> XA, H1B -> XB  (layout [e][ob16][p64][ci8])
    #pragma unroll
    for (int i = 0; i < 2; ++i) {
      const int e = e0 + i;
      const f32x4 bias = *(const f32x4*)(b1 + e*128 + o0 + g*4);
      const int ob = (o0 >> 3) + (g >> 1);
      #pragma unroll
      for (int pt = 0; pt < 4; ++pt) {
        const int p = pt*16 + r;
        f16x4 hA, hB;
        #pragma unroll
        for (int j = 0; j < 4; ++j) {
          hA[j] = (f16)fmaxf(acc[i][pt][j] + bias[j], 0.f);
          hB[j] = (f16)fmaxf(bcc[i][pt][j] + bias[j], 0.f);
        }
        *(f16x4*)(XA + e*16384 + (ob*64 + p)*16 + (g&1)*8) = hA;
        *(f16x4*)(XB + e*16384 + (ob*64 + p)*16 + (g&1)*8) = hB;
      }
    }
    __syncthreads();

    // ---- L2A: XA(H1A) -> H2
    #pragma unroll
    for (int s = 0; s < 3; ++s) {
      const int f  = wave*3 + s;
      const int e  = f / 12, ot = (f % 12) >> 2, pt = f & 3;
      const int p  = pt*16 + r;
      f32x4 a2 = {0.f,0.f,0.f,0.f};
      #pragma unroll
      for (int ks = 0; ks < 4; ++ks) {
        const int kb = ks*4 + g;
        f16x8 a  = *(const f16x8*)(W2s + (size_t)((e*16 + kb)*48 + ot*16 + r)*8);
        f16x8 bf = *(const f16x8*)(XA + e*16384 + (kb*64 + p)*16);
        a2 = MFMA16(a, bf, a2);
      }
      const f32x4 bias = *(const f32x4*)(b2 + e*48 + ot*16 + g*4);
      const int hb = ot*2 + (g >> 1);
      f16x4 hv;
      #pragma unroll
      for (int j = 0; j < 4; ++j) hv[j] = (f16)fmaxf(a2[j] + bias[j], 0.f);
      *(f16x4*)(H2 + e*8192 + (hb*64 + p)*16 + (g&1)*8) = hv;
    }
    __syncthreads();                   // H2A ready; XA free

    // ---- L3A loads FIRST (older than pf in vmcnt order), then pf issue
    f16x8 a3[4][2];  f32x4 b3v[4];  float weA[4], weB[4];
    if (wave < 4) {
      #pragma unroll
      for (int e = 0; e < 4; ++e) {
        a3[e][0] = *(const f16x8*)(W3s + (size_t)((e*8 + g)*16 + r)*8);
        a3[e][1] = *(const f16x8*)(W3s + (size_t)((e*8 + 4 + g)*16 + r)*8);
        b3v[e]   = *(const f32x4*)(b3 + e*16 + g*4);
        weA[e]   = wgt[(bA*4 + mA)*4 + e];
        weB[e]   = wgt[(bB*4 + mB)*4 + e];
      }
    }
    u32x4 pfa0, pfa1, pfa2, pfa3, pfb0, pfb1, pfb2, pfb3;
    if (it < 7) {
      const u32x4* sA = (const u32x4*)(Xt + (size_t)(bmtA+2) * 32768);
      const u32x4* sB = (const u32x4*)(Xt + (size_t)(bmtB+2) * 32768);
      pfa0 = __builtin_nontemporal_load(sA + tid);
      pfa1 = __builtin_nontemporal_load(sA + tid + 1024);
      pfa2 = __builtin_nontemporal_load(sA + tid + 2048);
      pfa3 = __builtin_nontemporal_load(sA + tid + 3072);
      pfb0 = __builtin_nontemporal_load(sB + tid);
      pfb1 = __builtin_nontemporal_load(sB + tid + 1024);
      pfb2 = __builtin_nontemporal_load(sB + tid + 2048);
      pfb3 = __builtin_nontemporal_load(sB + tid + 3072);
    }
    // ---- L3A + weighted combine -> outA (waves 0-3, pt = wave)
    if (wave < 4) {
      const int pt = wave, p = pt*16 + r;
      f32x4 sacc = {0.f,0.f,0.f,0.f};
      #pragma unroll
      for (int e = 0; e < 4; ++e) {
        f32x4 v3 = {0.f,0.f,0.f,0.f};
        v3 = MFMA16(a3[e][0], *(const f16x8*)(H2 + e*8192 + (g*64 + p)*16), v3);
        v3 = MFMA16(a3[e][1], *(const f16x8*)(H2 + e*8192 + ((4+g)*64 + p)*16), v3);
        #pragma unroll
        for (int j = 0; j < 4; ++j) sacc[j] += weA[e] * (v3[j] + b3v[e][j]);
      }
      #pragma unroll
      for (int j = 0; j < 4; ++j)
        __builtin_nontemporal_store(sacc[j],
            out + (((size_t)bA*16 + g*4 + j)*4 + mA)*4096 + (size_t)tileA*64 + p);
    }
    __syncthreads();                   // L3A's H2 reads done

    // ---- L2B: XB(H1B) -> H2
    #pragma unroll
    for (int s = 0; s < 3; ++s) {
      const int f  = wave*3 + s;
      const int e  = f / 12, ot = (f % 12) >> 2, pt = f & 3;
      const int p  = pt*16 + r;
      f32x4 a2 = {0.f,0.f,0.f,0.f};
      #pragma unroll
      for (int ks = 0; ks < 4; ++ks) {
        const int kb = ks*4 + g;
        f16x8 a  = *(const f16x8*)(W2s + (size_t)((e*16 + kb)*48 + ot*16 + r)*8);
        f16x8 bf = *(const f16x8*)(XB + e*16384 + (kb*64 + p)*16);
        a2 = MFMA16(a, bf, a2);
      }
      const f32x4 bias = *(const f32x4*)(b2 + e*48 + ot*16 + g*4);
      const int hb = ot*2 + (g >> 1);
      f16x4 hv;
      #pragma unroll
      for (int j = 0; j < 4; ++j) hv[j] = (f16)fmaxf(a2[j] + bias[j], 0.f);
      *(f16x4*)(H2 + e*8192 + (hb*64 + p)*16 + (g&1)*8) = hv;
    }
    __syncthreads();                   // H2B ready; XB free

    // ---- stage next pair into XA/XB; L3B + outB
    if (it < 7) {
      *(u32x4*)(XA + tid*16)         = pfa0;
      *(u32x4*)(XA + tid*16 + 16384) = pfa1;
      *(u32x4*)(XA + tid*16 + 32768) = pfa2;
      *(u32x4*)(XA + tid*16 + 49152) = pfa3;
      *(u32x4*)(XB + tid*16)         = pfb0;
      *(u32x4*)(XB + tid*16 + 16384) = pfb1;
      *(u32x4*)(XB + tid*16 + 32768) = pfb2;
      *(u32x4*)(XB + tid*16 + 49152) = pfb3;
    }
    if (wave < 4) {
      const int pt = wave, p = pt*16 + r;
      f32x4 sacc = {0.f,0.f,0.f,0.f};
      #pragma unroll
      for (int e = 0; e < 4; ++e) {
        f32x4 v3 = {0.f,0.f,0.f,0.f};
        v3 = MFMA16(a3[e][0], *(const f16x8*)(H2 + e*8192 + (g*64 + p)*16), v3);
        v3 = MFMA16(a3[e][1], *(const f16x8*)(H2 + e*8192 + ((4+g)*64 + p)*16), v3);
        #pragma unroll
        for (int j = 0; j < 4; ++j) sacc[j] += weB[e] * (v3[j] + b3v[e][j]);
      }
      #pragma unroll
      for (int j = 0; j < 4; ++j)
        __builtin_nontemporal_store(sacc[j],
            out + (((size_t)bB*16 + g*4 + j)*4 + mB)*4096 + (size_t)tileB*64 + p);
    }
  }
}

// ---------------- launcher ----------------
extern "C" void kernel_launch(void* const* d_in, const int* in_sizes, int n_in,
                              void* d_out, int out_size, void* d_ws, size_t ws_size,
                              hipStream_t stream) {
  const float* x   = (const float*)d_in[0];
  const float* W1  = (const float*)d_in[1];
  const float* b1  = (const float*)d_in[2];
  const float* W2  = (const float*)d_in[3];
  const float* b2  = (const float*)d_in[4];
  const float* W3  = (const float*)d_in[5];
  const float* b3  = (const float*)d_in[6];
  const float* Wg1 = (const float*)d_in[7];
  const float* bg1 = (const float*)d_in[8];
  const float* Wg2 = (const float*)d_in[9];
  const float* bg2 = (const float*)d_in[10];
  float* out = (float*)d_out;

  char* ws = (char*)d_ws;
  float* wgt     = (float*)ws;                         //      1 KiB [b][m][e]
  f16*   W1s     = (f16*)(ws + 4096);                  //    512 KiB
  f16*   W2s     = (f16*)(ws + 4096 + 524288);         //     48 KiB
  f16*   W3s     = (f16*)(ws + 4096 + 524288 + 49152); //      8 KiB
  float* partial = (float*)(ws + (1u<<20));            //    128 KiB [bm][c]
  f16*   Xt      = (f16*)(ws + (16u<<20));             //    256 MiB [bmt][kb][p][ci]

  (void)hipFuncSetAttribute(reinterpret_cast<const void*>(moe_kernel),
                            hipFuncAttributeMaxDynamicSharedMemorySize, 163840);

  prep_kernel<<<(262144 + 24576 + 4096 + 255)/256, 256, 0, stream>>>(W1, W2, W3, W1s, W2s, W3s);
  xprep_kernel<<<64*64, 1024, 0, stream>>>(x, Xt, partial);
  gate_kernel<<<BDIM, 256, 0, stream>>>(partial, Wg1, bg1, Wg2, bg2, wgt);
  moe_kernel<<<256, 1024, 163840, stream>>>(Xt, W1s, W2s, W3s, b1, b2, b3, wgt, out);
}

// Round 10
// 512.538 us; speedup vs baseline: 1.9569x; 1.9569x over previous
//
#include <hip/hip_runtime.h>

typedef _Float16 f16;
typedef f16 f16x8 __attribute__((ext_vector_type(8)));
typedef f16 f16x4 __attribute__((ext_vector_type(4)));
typedef float f32x4 __attribute__((ext_vector_type(4)));
typedef unsigned int u32x4 __attribute__((ext_vector_type(4)));

#define BDIM 16
#define MDIM 4
#define NDIM 4096
#define NB   64
#define NTILES (NDIM/NB)          // 64
#define NBMT  (BDIM*MDIM*NTILES)  // 4096

#define MFMA16(a,b,c) __builtin_amdgcn_mfma_f32_16x16x32_f16(a, b, c, 0, 0, 0)

// async global->LDS DMA, 16 B/lane; LDS dest is wave-uniform base + lane*16
__device__ __forceinline__ void gload_lds16(const void* g, void* l) {
  __builtin_amdgcn_global_load_lds(
      (const __attribute__((address_space(1))) unsigned int*)g,
      (__attribute__((address_space(3))) unsigned int*)l,
      16, 0, 0);
}

// ---------------- prep: fp32 weights -> f16 fragment layout ----------------
// W1s: [e][kb(64)][o(128)][ki(8)]   W2s: [e][kb(16)][o(48)][ki(8)]
// W3s: [e][kb(8)][o(16)][ki(8)] (K padded 48->64 with zeros)
__global__ __launch_bounds__(256) void prep_kernel(
    const float* __restrict__ W1, const float* __restrict__ W2, const float* __restrict__ W3,
    f16* __restrict__ W1s, f16* __restrict__ W2s, f16* __restrict__ W3s)
{
  int i = blockIdx.x * 256 + threadIdx.x;
  if (i < 262144) {
    int ki = i & 7; int rest = i >> 3;
    int o = rest & 127; rest >>= 7;
    int kb = rest & 63; int e = rest >> 6;
    W1s[i] = (f16)W1[(e*128 + o)*512 + kb*8 + ki];
  } else if (i < 262144 + 24576) {
    int j = i - 262144;
    int ki = j & 7; int rest = j >> 3;
    int o = rest % 48; rest /= 48;
    int kb = rest & 15; int e = rest >> 4;
    W2s[j] = (f16)W2[(e*48 + o)*128 + kb*8 + ki];
  } else if (i < 262144 + 24576 + 4096) {
    int j = i - 262144 - 24576;
    int ki = j & 7; int rest = j >> 3;
    int o = rest & 15; rest >>= 4;
    int kb = rest & 7; int e = rest >> 3;
    int k = kb*8 + ki;
    W3s[j] = (k < 48) ? (f16)W3[(e*16 + o)*48 + k] : (f16)0.f;
  }
}

// ---------------- xprep: coalesced read + register transpose --------------
// block = (bm, cb): 8 channels x all 4096 n; 1024 threads, one n-quad each.
// Plain cached loads/stores (nt hurt here, R8). Emits pooled sums too.
__global__ __launch_bounds__(1024) void xprep_kernel(
    const float* __restrict__ x, f16* __restrict__ Xt, float* __restrict__ partial)
{
  const int bid = blockIdx.x;            // bm*64 + cb
  const int cb  = bid & 63;
  const int bm  = bid >> 6;              // b*4 + m
  const int b   = bm >> 2, m = bm & 3;
  const int t   = threadIdx.x;
  const int lane = t & 63, wid = t >> 6;

  __shared__ float red[16][8];

  const int n0 = t*4;
  f32x4 v[8];
  #pragma unroll
  for (int ci = 0; ci < 8; ++ci)
    v[ci] = *(const f32x4*)(x + (((size_t)(b*512 + cb*8 + ci))*4 + m)*4096 + n0);

  float s[8];
  #pragma unroll
  for (int ci = 0; ci < 8; ++ci) s[ci] = v[ci][0]+v[ci][1]+v[ci][2]+v[ci][3];

  const int tile = n0 >> 6, p = n0 & 63;
  const size_t obase = (((size_t)bm*64 + tile)*64 + cb)*64;
  #pragma unroll
  for (int i = 0; i < 4; ++i) {
    f16x8 o;
    #pragma unroll
    for (int ci = 0; ci < 8; ++ci) o[ci] = (f16)v[ci][i];
    *(f16x8*)(Xt + (obase + p + i)*8) = o;
  }

  #pragma unroll
  for (int off = 32; off; off >>= 1)
    #pragma unroll
    for (int ci = 0; ci < 8; ++ci) s[ci] += __shfl_down(s[ci], off);
  if (lane == 0)
    #pragma unroll
    for (int ci = 0; ci < 8; ++ci) red[wid][ci] = s[ci];
  __syncthreads();
  if (t < 8) {
    float a = 0.f;
    #pragma unroll
    for (int w = 0; w < 16; ++w) a += red[w][t];
    partial[(size_t)bm*512 + cb*8 + t] = a;
  }
}

// ---------------- gate: pooled -> MLP + softmax (torch reshape quirk) -----
__global__ __launch_bounds__(256) void gate_kernel(
    const float* __restrict__ partial, const float* __restrict__ Wg1,
    const float* __restrict__ bg1, const float* __restrict__ Wg2,
    const float* __restrict__ bg2, float* __restrict__ wgt)
{
  __shared__ float pl[512*4];   // [c][m]
  __shared__ float g1[128*4];   // [o][m]
  __shared__ float g2[16];      // [e][m]
  const int b = blockIdx.x, tid = threadIdx.x;
  for (int i = tid; i < 2048; i += 256) {
    int c = i >> 2, mm = i & 3;
    pl[c*4 + mm] = partial[(size_t)(b*4 + mm)*512 + c] * (1.0f/4096.0f);
  }
  __syncthreads();
  #pragma unroll
  for (int u = 0; u < 2; ++u) {
    int idx = u*256 + tid;
    int o = idx >> 2, mm = idx & 3;
    float acc = bg1[o];
    for (int c = 0; c < 512; ++c) acc += Wg1[o*512 + c] * pl[c*4 + mm];
    g1[o*4 + mm] = fmaxf(acc, 0.f);
  }
  __syncthreads();
  if (tid < 16) {
    int e = tid >> 2, mm = tid & 3;
    float acc = bg2[e];
    for (int o = 0; o < 128; ++o) acc += Wg2[e*128 + o] * g1[o*4 + mm];
    g2[e*4 + mm] = acc;
  }
  __syncthreads();
  if (tid < 4) {
    int mrow = tid;
    float v0 = g2[mrow*4+0], v1 = g2[mrow*4+1], v2 = g2[mrow*4+2], v3 = g2[mrow*4+3];
    float mx = fmaxf(fmaxf(v0,v1), fmaxf(v2,v3));
    float e0 = expf(v0-mx), e1 = expf(v1-mx), e2 = expf(v2-mx), e3 = expf(v3-mx);
    float inv = 1.0f / (e0+e1+e2+e3);
    wgt[b*16 + mrow*4 + 0] = e0*inv;
    wgt[b*16 + mrow*4 + 1] = e1*inv;
    wgt[b*16 + mrow*4 + 2] = e2*inv;
    wgt[b*16 + mrow*4 + 3] = e3*inv;
  }
}

// ---------------- moe: persistent, DMA-prefetched tiles, combine fused ----
// 256 blocks x 1024 thr (16 waves), 160 KiB LDS, 1 block/CU, 16 tiles/block.
// LDS: X0 64K | X1 64K | H2 32K. H1 overlays the just-consumed X buffer.
// Next tile staged via global_load_lds DMA (zero VGPR) into the free X
// buffer; overlaps Phase A. Phase A kept register-lean (acc 32 + ~40 misc,
// unroll window bounded) so NOTHING spills -- R6/R9's 450-680 MB WRITE_SIZE
// was scratch spill traffic that also thrashed W1s out of L2.
__global__ __launch_bounds__(1024, 4) void moe_kernel(
    const f16* __restrict__ Xt,
    const f16* __restrict__ W1s, const f16* __restrict__ W2s, const f16* __restrict__ W3s,
    const float* __restrict__ b1, const float* __restrict__ b2, const float* __restrict__ b3,
    const float* __restrict__ wgt, float* __restrict__ out)
{
  extern __shared__ __align__(16) char smem[];     // 163840 B
  char* H2 = smem + 131072;

  const int tid  = threadIdx.x;
  const int wave = tid >> 6, lane = tid & 63;
  const int g = lane >> 4, r = lane & 15;
  const int eh = wave >> 3;                        // experts 2eh, 2eh+1
  const int o0 = (wave & 7) * 16;
  const int e0 = eh*2, e1 = eh*2 + 1;

  // zero H2's K-pad (hb 6,7 per e) once; L2 layer never writes hb>5
  if (tid < 512) {
    int e = tid >> 7, off = tid & 127;
    *(u32x4*)(H2 + e*8192 + 6144 + off*16) = (u32x4){0u,0u,0u,0u};
  }

  const int bmt0 = blockIdx.x * 16;
  // prologue: DMA tile bmt0 -> X0  (per wave: 4 x 1 KiB rows)
  {
    const char* src = (const char*)Xt + (size_t)bmt0 * 65536;
    #pragma unroll
    for (int j = 0; j < 4; ++j)
      gload_lds16(src + tid*16 + j*16384, smem + wave*1024 + j*16384);
  }
  int cur = 0;

  #pragma unroll 1
  for (int it = 0; it < 16; ++it) {
    const int bmt  = bmt0 + it;
    const int tile = bmt & 63, m = (bmt >> 6) & 3, b = bmt >> 8;
    char* Xcur = smem + cur*65536;
    char* Xoth = smem + (cur^1)*65536;

    __syncthreads();                     // drains DMA: Xcur staged; Xoth free

    // issue next tile's DMA into Xoth (in flight across Phase A)
    if (it < 15) {
      const char* src = (const char*)Xt + (size_t)(bmt+1) * 65536;
      #pragma unroll
      for (int j = 0; j < 4; ++j)
        gload_lds16(src + tid*16 + j*16384, Xoth + wave*1024 + j*16384);
    }

    // ---- Phase A: L1 for 2 experts, o-strip 16, all 64 p; barrier-free
    f32x4 acc[2][4];
    #pragma unroll
    for (int i = 0; i < 2; ++i)
      #pragma unroll
      for (int pt = 0; pt < 4; ++pt) acc[i][pt] = (f32x4){0.f,0.f,0.f,0.f};

    const f16* Wb = W1s + (size_t)(o0 + r)*8;
    #pragma unroll 2
    for (int ks = 0; ks < 16; ++ks) {
      const int kb = ks*4 + g;           // 0..63
      const f16x8 aw0 = *(const f16x8*)(Wb + ((size_t)(e0*64 + kb)*128)*8);
      const f16x8 aw1 = *(const f16x8*)(Wb + ((size_t)(e1*64 + kb)*128)*8);
      #pragma unroll
      for (int pt = 0; pt < 4; ++pt) {
        const f16x8 bf = *(const f16x8*)(Xcur + (kb*64 + pt*16 + r)*16);
        acc[0][pt] = MFMA16(aw0, bf, acc[0][pt]);
        acc[1][pt] = MFMA16(aw1, bf, acc[1][pt]);
      }
    }
    __syncthreads();                     // Xcur reads done -> reuse as H1

    // ---- H1 = relu(acc+b1) -> Xcur as [e][ob16][p64][ci8]
    #pragma unroll
    for (int i = 0; i < 2; ++i) {
      const int e = e0 + i;
      const f32x4 bias = *(const f32x4*)(b1 + e*128 + o0 + g*4);
      const int ob = (o0 >> 3) + (g >> 1);
      #pragma unroll
      for (int pt = 0; pt < 4; ++pt) {
        const int p = pt*16 + r;
        f16x4 hv;
        #pragma unroll
        for (int j = 0; j < 4; ++j) hv[j] = (f16)fmaxf(acc[i][pt][j] + bias[j], 0.f);
        *(f16x4*)(Xcur + e*16384 + (ob*64 + p)*16 + (g&1)*8) = hv;
      }
    }
    __syncthreads();

    // ---- L2: 48 fragments (4e x 3ot x 4pt), 3 per wave -> H2 [e][hb8][p][ci]
    #pragma unroll
    for (int s = 0; s < 3; ++s) {
      const int f  = wave*3 + s;
      const int e  = f / 12, ot = (f % 12) >> 2, pt = f & 3;
      const int p  = pt*16 + r;
      f32x4 a2 = {0.f,0.f,0.f,0.f};
      #pragma unroll
      for (int ks = 0; ks < 4; ++ks) {
        const int kb = ks*4 + g;
        f16x8 a  = *(const f16x8*)(W2s + (size_t)((e*16 + kb)*48 + ot*16 + r)*8);
        f16x8 bf = *(const f16x8*)(Xcur + e*16384 + (kb*64 + p)*16);
        a2 = MFMA16(a, bf, a2);
      }
      const f32x4 bias = *(const f32x4*)(b2 + e*48 + ot*16 + g*4);
      const int hb = ot*2 + (g >> 1);
      f16x4 hv;
      #pragma unroll
      for (int j = 0; j < 4; ++j) hv[j] = (f16)fmaxf(a2[j] + bias[j], 0.f);
      *(f16x4*)(H2 + e*8192 + (hb*64 + p)*16 + (g&1)*8) = hv;
    }
    __syncthreads();                     // H2 ready

    // ---- L3 + weighted combine -> out (waves 0-3, pt = wave)
    if (wave < 4) {
      const int pt = wave, p = pt*16 + r;
      f32x4 sacc = {0.f,0.f,0.f,0.f};
      #pragma unroll
      for (int e = 0; e < 4; ++e) {
        f32x4 a3 = {0.f,0.f,0.f,0.f};
        #pragma unroll
        for (int ks = 0; ks < 2; ++ks) {
          const int kb = ks*4 + g;
          f16x8 a  = *(const f16x8*)(W3s + (size_t)((e*8 + kb)*16 + r)*8);
          f16x8 bf = *(const f16x8*)(H2 + e*8192 + (kb*64 + p)*16);
          a3 = MFMA16(a, bf, a3);
        }
        const float we = wgt[(b*4 + m)*4 + e];
        const f32x4 bv = *(const f32x4*)(b3 + e*16 + g*4);
        #pragma unroll
        for (int j = 0; j < 4; ++j) sacc[j] += we * (a3[j] + bv[j]);
      }
      #pragma unroll
      for (int j = 0; j < 4; ++j) {
        const int o = g*4 + j;
        __builtin_nontemporal_store(sacc[j],
            out + (((size_t)b*16 + o)*4 + m)*4096 + (size_t)tile*64 + p);
      }
    }

    cur ^= 1;
  }
}

// ---------------- launcher ----------------
extern "C" void kernel_launch(void* const* d_in, const int* in_sizes, int n_in,
                              void* d_out, int out_size, void* d_ws, size_t ws_size,
                              hipStream_t stream) {
  const float* x   = (const float*)d_in[0];
  const float* W1  = (const float*)d_in[1];
  const float* b1  = (const float*)d_in[2];
  const float* W2  = (const float*)d_in[3];
  const float* b2  = (const float*)d_in[4];
  const float* W3  = (const float*)d_in[5];
  const float* b3  = (const float*)d_in[6];
  const float* Wg1 = (const float*)d_in[7];
  const float* bg1 = (const float*)d_in[8];
  const float* Wg2 = (const float*)d_in[9];
  const float* bg2 = (const float*)d_in[10];
  float* out = (float*)d_out;

  char* ws = (char*)d_ws;
  float* wgt     = (float*)ws;                         //      1 KiB [b][m][e]
  f16*   W1s     = (f16*)(ws + 4096);                  //    512 KiB
  f16*   W2s     = (f16*)(ws + 4096 + 524288);         //     48 KiB
  f16*   W3s     = (f16*)(ws + 4096 + 524288 + 49152); //      8 KiB
  float* partial = (float*)(ws + (1u<<20));            //    128 KiB [bm][c]
  f16*   Xt      = (f16*)(ws + (16u<<20));             //    256 MiB [bmt][kb][p][ci]

  (void)hipFuncSetAttribute(reinterpret_cast<const void*>(moe_kernel),
                            hipFuncAttributeMaxDynamicSharedMemorySize, 163840);

  prep_kernel<<<(262144 + 24576 + 4096 + 255)/256, 256, 0, stream>>>(W1, W2, W3, W1s, W2s, W3s);
  xprep_kernel<<<64*64, 1024, 0, stream>>>(x, Xt, partial);
  gate_kernel<<<BDIM, 256, 0, stream>>>(partial, Wg1, bg1, Wg2, bg2, wgt);
  moe_kernel<<<256, 1024, 163840, stream>>>(Xt, W1s, W2s, W3s, b1, b2, b3, wgt, out);
}